// Round 5
// baseline (76.192 us; speedup 1.0000x reference)
//
#include <hip/hip_runtime.h>
#include <math.h>

// Chamfer loss via MFMA: d2_ij = |x_i|^2 + |y_j|^2 - 2 x_i.y_j computed as a
// single v_mfma_f32_32x32x16_bf16 per 32x32 tile using bf16-split packing:
//  k0-2 : A=-2xh_c  B=yh_c      k3-5 : A=-2xl_c  B=yh_c
//  k6-8 : A=-2xh_c  B=yl_c      k9-11: A=-2xl_c  B=yl_c
//  k12  : A=1       B=y2h       k13  : A=1       B=y2l
//  k14  : A=x2h     B=1         k15  : A=x2l     B=1
// Sum over K = full d2 (split error ~1e-4 << 1.28e-2 threshold).
// VALU only does running row-min: 16 fmin per 1024 pairs.

typedef __attribute__((ext_vector_type(8)))  short  short8;
typedef __attribute__((ext_vector_type(16))) float  f32x16;

#define YS   4      // j-range splits per (dir,b)
#define WPB  4      // waves per block in the sweep kernel

static inline int roundup_h(int v, int a) { return (v + a - 1) / a * a; }

static __device__ __forceinline__ unsigned short f2bf(float f) {
    union { float f; unsigned int u; } v; v.f = f;
    unsigned int r = v.u + 0x7FFFu + ((v.u >> 16) & 1u);  // RNE
    return (unsigned short)(r >> 16);
}
static __device__ __forceinline__ float bf2f(unsigned short s) {
    union { unsigned int u; float f; } v; v.u = ((unsigned int)s) << 16;
    return v.f;
}
static __device__ __forceinline__ unsigned int pk2(unsigned short lo,
                                                   unsigned short hi) {
    return (unsigned int)lo | ((unsigned int)hi << 16);
}

// Per point: emit A-pattern and B-pattern 16xbf16 (32 B each).
__global__ __launch_bounds__(256) void pack_kernel(
    const float* __restrict__ pred, const float* __restrict__ targ,
    int B, int N, int M, int NpadP, int NpadT,
    unsigned short* __restrict__ aP, unsigned short* __restrict__ bP,
    unsigned short* __restrict__ aT, unsigned short* __restrict__ bT)
{
    const int padmax = (NpadP > NpadT) ? NpadP : NpadT;
    const int gid = blockIdx.x * 256 + threadIdx.x;
    if (gid >= B * padmax) return;
    const int b = gid / padmax, i = gid - b * padmax;

    for (int cloud = 0; cloud < 2; ++cloud) {
        const int cnt  = cloud ? M : N;
        const int npad = cloud ? NpadT : NpadP;
        if (i >= npad) continue;
        // padding duplicates the last point: harmless for min reductions
        const float* src = (cloud ? targ : pred) +
                           ((size_t)b * cnt + min(i, cnt - 1)) * 3;
        unsigned short* A  = (cloud ? aT : aP) + ((size_t)b * npad + i) * 16;
        unsigned short* Bk = (cloud ? bT : bP) + ((size_t)b * npad + i) * 16;

        const float xs[3] = {src[0], src[1], src[2]};
        const float n2 = xs[0]*xs[0] + xs[1]*xs[1] + xs[2]*xs[2];
        unsigned short th[3], tl[3], yh[3], yl[3];
        #pragma unroll
        for (int c = 0; c < 3; ++c) {
            const float t = -2.0f * xs[c];
            th[c] = f2bf(t);     tl[c] = f2bf(t - bf2f(th[c]));
            yh[c] = f2bf(xs[c]); yl[c] = f2bf(xs[c] - bf2f(yh[c]));
        }
        const unsigned short n2h = f2bf(n2);
        const unsigned short n2l = f2bf(n2 - bf2f(n2h));
        const unsigned short ONE = 0x3F80;

        uint4 alo, ahi, blo, bhi;
        alo.x = pk2(th[0], th[1]); alo.y = pk2(th[2], tl[0]);
        alo.z = pk2(tl[1], tl[2]); alo.w = pk2(th[0], th[1]);
        ahi.x = pk2(th[2], tl[0]); ahi.y = pk2(tl[1], tl[2]);
        ahi.z = pk2(ONE,  ONE);    ahi.w = pk2(n2h,  n2l);
        blo.x = pk2(yh[0], yh[1]); blo.y = pk2(yh[2], yh[0]);
        blo.z = pk2(yh[1], yh[2]); blo.w = pk2(yl[0], yl[1]);
        bhi.x = pk2(yl[2], yl[0]); bhi.y = pk2(yl[1], yl[2]);
        bhi.z = pk2(n2h,  n2l);    bhi.w = pk2(ONE,  ONE);

        *(uint4*)(A)      = alo;  *(uint4*)(A + 8)  = ahi;
        *(uint4*)(Bk)     = blo;  *(uint4*)(Bk + 8) = bhi;
    }
}

// Wave = (dir, b, js, strip-pair). 64 rows (2 MFMA strips), sweeps its
// j-chunk of 32-col tiles. A-frags loop-invariant in regs; B-frags direct
// global loads (L2-resident) with 1-deep prefetch. Writes per-row raw d2
// minima to rowpart[((dir*B+b)*YS+js)*NpadMax + row].
__global__ __launch_bounds__(256, 4) void mfma_sweep(
    const unsigned short* __restrict__ aP, const unsigned short* __restrict__ bP,
    const unsigned short* __restrict__ aT, const unsigned short* __restrict__ bT,
    int B, int N, int M, int NpadP, int NpadT, int NpadMax,
    float* __restrict__ rowpart)
{
    const int wid  = blockIdx.x * WPB + (threadIdx.x >> 6);
    const int lane = threadIdx.x & 63;
    const int lc   = lane & 31, h = lane >> 5;

    const int SP = NpadMax / 64;
    int t = wid;
    const int sp  = t % SP;  t /= SP;
    const int js  = t % YS;  t /= YS;
    const int b   = t % B;   t /= B;
    const int dir = t;
    if (dir > 1) return;

    const unsigned short* Xp = (dir == 0) ? aP : aT;
    const unsigned short* Yp = (dir == 0) ? bT : bP;
    const int NpadX = (dir == 0) ? NpadP : NpadT;
    const int NpadY = (dir == 0) ? NpadT : NpadP;
    const int Nx    = (dir == 0) ? N : M;
    if (sp * 64 >= NpadX) return;

    // A-frags: row = lane&31, k = (lane>>5)*8 + e  (32x32x16 bf16 layout)
    const size_t xoff = ((size_t)b * NpadX + sp * 64 + lc) * 16 + (size_t)h * 8;
    const short8 a0 = *reinterpret_cast<const short8*>(Xp + xoff);
    const short8 a1 = *reinterpret_cast<const short8*>(Xp + xoff + 32 * 16);

    const int TM  = NpadY / 32;
    const int nt0 = (TM + YS - 1) / YS;
    const int t0  = js * nt0;
    const int nt  = min(TM - t0, nt0);
    if (nt <= 0) return;  // combine guards this js

    f32x16 z, rm0, rm1;
    #pragma unroll
    for (int r = 0; r < 16; ++r) {
        z[r] = 0.0f; rm0[r] = __builtin_inff(); rm1[r] = __builtin_inff();
    }

    // B-frag: col = lane&31, k = (lane>>5)*8 + e
    const unsigned short* yptr =
        Yp + ((size_t)b * NpadY + (size_t)t0 * 32 + lc) * 16 + (size_t)h * 8;
    short8 bcur = *reinterpret_cast<const short8*>(yptr);
    yptr += 32 * 16;

    for (int tt = 0; tt < nt; ++tt) {
        const short8 bnxt = *reinterpret_cast<const short8*>(yptr); // slack-padded
        yptr += 32 * 16;
        const f32x16 d0 =
            __builtin_amdgcn_mfma_f32_32x32x16_bf16(a0, bcur, z, 0, 0, 0);
        const f32x16 d1 =
            __builtin_amdgcn_mfma_f32_32x32x16_bf16(a1, bcur, z, 0, 0, 0);
        #pragma unroll
        for (int r = 0; r < 16; ++r) {
            rm0[r] = fminf(rm0[r], d0[r]);
            rm1[r] = fminf(rm1[r], d1[r]);
        }
        bcur = bnxt;
    }

    // cross-lane min over the 32-lane half (cols), then store per-row minima.
    // D layout: col=lane&31, row=(r&3)+8*(r>>2)+4*(lane>>5)
    const size_t outb = (((size_t)dir * B + b) * YS + js) * (size_t)NpadMax;
    #pragma unroll
    for (int r = 0; r < 16; ++r) {
        float v0 = rm0[r], v1 = rm1[r];
        #pragma unroll
        for (int mk = 1; mk <= 16; mk <<= 1) {
            v0 = fminf(v0, __shfl_xor(v0, mk, 64));
            v1 = fminf(v1, __shfl_xor(v1, mk, 64));
        }
        const int rr   = (r & 3) + 8 * (r >> 2) + 4 * h;
        const int row0 = sp * 64 + rr;
        if (lc == 0) {
            if (row0 < Nx)      rowpart[outb + row0]      = v0;
            if (row0 + 32 < Nx) rowpart[outb + row0 + 32] = v1;
        }
    }
}

__global__ __launch_bounds__(256) void combine_kernel(
    const float* __restrict__ rowpart, int B, int N, int M,
    int NpadP, int NpadT, int NpadMax,
    float invBN, float invBM, float* __restrict__ partial)
{
    const int tid = threadIdx.x;
    const int tot = 2 * B * NpadMax;
    float acc = 0.f;
    for (int idx = blockIdx.x * 256 + tid; idx < tot; idx += gridDim.x * 256) {
        const int row = idx % NpadMax;
        const int rem = idx / NpadMax;
        const int b   = rem % B;
        const int dir = rem / B;
        const int Nx  = (dir == 0) ? N : M;
        if (row >= Nx) continue;
        const int NpadY = (dir == 0) ? NpadT : NpadP;
        const int TM  = NpadY / 32;
        const int nt0 = (TM + YS - 1) / YS;
        float m = __builtin_inff();
        #pragma unroll
        for (int js = 0; js < YS; ++js)
            if (js * nt0 < TM)
                m = fminf(m, rowpart[(((size_t)dir * B + b) * YS + js)
                                     * (size_t)NpadMax + row]);
        acc += fmaxf(m, 0.f) * ((dir == 0) ? invBN : invBM);
    }
    __shared__ float sb[256];
    sb[tid] = acc; __syncthreads();
    for (int off2 = 128; off2 > 0; off2 >>= 1) {
        if (tid < off2) sb[tid] += sb[tid + off2];
        __syncthreads();
    }
    if (tid == 0) partial[blockIdx.x] = sb[0];
}

__global__ void finalize_kernel(const float* __restrict__ partial, int np,
                                const float* __restrict__ fbpp, int Bf,
                                const void* __restrict__ lamp,
                                float* __restrict__ out)
{
    __shared__ float sb[256];
    const int tid = threadIdx.x;
    float acc = 0.f;
    for (int i = tid; i < np; i += 256) acc += partial[i];
    sb[tid] = acc;
    __syncthreads();
    for (int off = 128; off > 0; off >>= 1) {
        if (tid < off) sb[tid] += sb[tid + off];
        __syncthreads();
    }
    if (tid == 0) {
        const int li = *(const int*)lamp;
        const float lam = (li >= -1000000 && li <= 1000000)
                            ? (float)li : *(const float*)lamp;
        float fm = 0.f;
        for (int i = 0; i < Bf; ++i) fm += fbpp[i];
        fm /= (float)Bf;
        out[0] = sb[0] + lam * fm;
    }
}

extern "C" void kernel_launch(void* const* d_in, const int* in_sizes, int n_in,
                              void* d_out, int out_size, void* d_ws, size_t ws_size,
                              hipStream_t stream) {
    const float* pred = (const float*)d_in[0];
    const float* targ = (const float*)d_in[1];
    const float* fbpp = (const float*)d_in[2];
    const void*  lamp = d_in[3];

    const int B = in_sizes[2];
    const int N = in_sizes[0] / (3 * B);
    const int M = in_sizes[1] / (3 * B);
    const int NpadP = roundup_h(N, 64);
    const int NpadT = roundup_h(M, 64);
    const int NpadMax = (NpadP > NpadT) ? NpadP : NpadT;

    // ---- workspace layout (packs have +64-point slack for prefetch OOB) ----
    size_t o = 0;
    auto take = [&](size_t bytes) {
        size_t r = o; o += (bytes + 255) & ~(size_t)255; return r;
    };
    unsigned short* aP = (unsigned short*)((char*)d_ws +
                         take(((size_t)B * NpadP + 64) * 32));
    unsigned short* bP = (unsigned short*)((char*)d_ws +
                         take(((size_t)B * NpadP + 64) * 32));
    unsigned short* aT = (unsigned short*)((char*)d_ws +
                         take(((size_t)B * NpadT + 64) * 32));
    unsigned short* bT = (unsigned short*)((char*)d_ws +
                         take(((size_t)B * NpadT + 64) * 32));
    float* rowpart = (float*)((char*)d_ws +
                     take((size_t)2 * B * YS * NpadMax * sizeof(float)));
    float* partial = (float*)((char*)d_ws + take(256 * sizeof(float)));
    (void)ws_size;

    // ---- 1) pack both clouds into A/B MFMA K-patterns ----
    const int padmax = NpadMax;
    pack_kernel<<<(B * padmax + 255) / 256, 256, 0, stream>>>(
        pred, targ, B, N, M, NpadP, NpadT, aP, bP, aT, bT);

    // ---- 2) MFMA pair sweep (both directions) ----
    const int SP = NpadMax / 64;
    const int waves = 2 * B * YS * SP;
    mfma_sweep<<<(waves + WPB - 1) / WPB, WPB * 64, 0, stream>>>(
        aP, bP, aT, bT, B, N, M, NpadP, NpadT, NpadMax, rowpart);

    // ---- 3) combine js splits + clamp + weighted sum ----
    combine_kernel<<<256, 256, 0, stream>>>(
        rowpart, B, N, M, NpadP, NpadT, NpadMax,
        1.f / ((float)B * (float)N), 1.f / ((float)B * (float)M), partial);

    // ---- 4) finalize ----
    finalize_kernel<<<1, 256, 0, stream>>>(partial, 256, fbpp, B, lamp,
                                           (float*)d_out);
}

// Round 7
// 51.034 us; speedup vs baseline: 1.4930x; 1.4930x over previous
//
#include <hip/hip_runtime.h>
#include <math.h>

// Chamfer loss via MFMA: d2_ij = |x_i|^2 + |y_j|^2 - 2 x_i.y_j as ONE
// v_mfma_f32_32x32x16_bf16 per 32x32 tile using bf16-split K-packing:
//  k0-2 : A=-2xh_c  B=yh_c      k3-5 : A=-2xl_c  B=yh_c
//  k6-8 : A=-2xh_c  B=yl_c      k9-11: A=-2xl_c  B=yl_c
//  k12  : A=1 B=y2h   k13: A=1 B=y2l   k14: A=x2h B=1   k15: A=x2l B=1
// (packing verified round 5, absmax 0.0)
// Round-7 fix vs round 6: stage-time permute of the y-pack so each lane's
// linear LDS read (lane*16B) yields point=lane&31, khalf=lane>>5.
// Round 6 read point=lane/2, khalf=lane&1 -> scrambled K (absmax 4.7e-2).

typedef __attribute__((ext_vector_type(8)))  short  short8;
typedef __attribute__((ext_vector_type(16))) float  f32x16;

#define YS      4     // j-range splits per (dir,b)
#define RPB     128   // rows per block = 4 waves * 32
#define YTILE_T 32    // 32-col tiles per LDS fill (1024 pts, 32 KB)

static inline int roundup_h(int v, int a) { return (v + a - 1) / a * a; }

static __device__ __forceinline__ unsigned short f2bf(float f) {
    union { float f; unsigned int u; } v; v.f = f;
    unsigned int r = v.u + 0x7FFFu + ((v.u >> 16) & 1u);  // RNE
    return (unsigned short)(r >> 16);
}
static __device__ __forceinline__ float bf2f(unsigned short s) {
    union { unsigned int u; float f; } v; v.u = ((unsigned int)s) << 16;
    return v.f;
}
static __device__ __forceinline__ unsigned int pk2(unsigned short lo,
                                                   unsigned short hi) {
    return (unsigned int)lo | ((unsigned int)hi << 16);
}

__global__ __launch_bounds__(256) void pack_kernel(
    const float* __restrict__ pred, const float* __restrict__ targ,
    int B, int N, int M, int NpadP, int NpadT,
    unsigned short* __restrict__ aP, unsigned short* __restrict__ bP,
    unsigned short* __restrict__ aT, unsigned short* __restrict__ bT)
{
    const int padmax = (NpadP > NpadT) ? NpadP : NpadT;
    const int gid = blockIdx.x * 256 + threadIdx.x;
    if (gid >= B * padmax) return;
    const int b = gid / padmax, i = gid - b * padmax;

    for (int cloud = 0; cloud < 2; ++cloud) {
        const int cnt  = cloud ? M : N;
        const int npad = cloud ? NpadT : NpadP;
        if (i >= npad) continue;
        // padding duplicates the last point: harmless for min reductions
        const float* src = (cloud ? targ : pred) +
                           ((size_t)b * cnt + min(i, cnt - 1)) * 3;
        unsigned short* A  = (cloud ? aT : aP) + ((size_t)b * npad + i) * 16;
        unsigned short* Bk = (cloud ? bT : bP) + ((size_t)b * npad + i) * 16;

        const float xs[3] = {src[0], src[1], src[2]};
        const float n2 = xs[0]*xs[0] + xs[1]*xs[1] + xs[2]*xs[2];
        unsigned short th[3], tl[3], yh[3], yl[3];
        #pragma unroll
        for (int c = 0; c < 3; ++c) {
            const float t = -2.0f * xs[c];
            th[c] = f2bf(t);     tl[c] = f2bf(t - bf2f(th[c]));
            yh[c] = f2bf(xs[c]); yl[c] = f2bf(xs[c] - bf2f(yh[c]));
        }
        const unsigned short n2h = f2bf(n2);
        const unsigned short n2l = f2bf(n2 - bf2f(n2h));
        const unsigned short ONE = 0x3F80;

        uint4 alo, ahi, blo, bhi;
        alo.x = pk2(th[0], th[1]); alo.y = pk2(th[2], tl[0]);
        alo.z = pk2(tl[1], tl[2]); alo.w = pk2(th[0], th[1]);
        ahi.x = pk2(th[2], tl[0]); ahi.y = pk2(tl[1], tl[2]);
        ahi.z = pk2(ONE,  ONE);    ahi.w = pk2(n2h,  n2l);
        blo.x = pk2(yh[0], yh[1]); blo.y = pk2(yh[2], yh[0]);
        blo.z = pk2(yh[1], yh[2]); blo.w = pk2(yl[0], yl[1]);
        bhi.x = pk2(yl[2], yl[0]); bhi.y = pk2(yl[1], yl[2]);
        bhi.z = pk2(n2h,  n2l);    bhi.w = pk2(ONE,  ONE);

        *(uint4*)(A)      = alo;  *(uint4*)(A + 8)  = ahi;
        *(uint4*)(Bk)     = blo;  *(uint4*)(Bk + 8) = bhi;
    }
}

// Block = (dir, b, js, row-block of 128). 4 waves, wave w owns rows
// [sp*128 + w*32, +32). Y-pack staged (permuted) in LDS, shared by all
// waves. Per 32-col tile: 1 linear ds_read_b128 + 1 MFMA + 8 fused min3.
__global__ __launch_bounds__(256) void mfma_sweep(
    const unsigned short* __restrict__ aP, const unsigned short* __restrict__ bP,
    const unsigned short* __restrict__ aT, const unsigned short* __restrict__ bT,
    int B, int N, int M, int NpadP, int NpadT, int NpadMax,
    float* __restrict__ rowpart)
{
    const int tid  = threadIdx.x;
    const int w    = tid >> 6;
    const int lane = tid & 63;
    const int lc   = lane & 31, h = lane >> 5;

    const int SP = NpadMax / RPB;
    int t = blockIdx.x;
    const int sp  = t % SP;  t /= SP;
    const int js  = t % YS;  t /= YS;
    const int b   = t % B;   t /= B;
    const int dir = t;

    const unsigned short* Xp = (dir == 0) ? aP : aT;
    const unsigned short* Yp = (dir == 0) ? bT : bP;
    const int NpadX = (dir == 0) ? NpadP : NpadT;
    const int NpadY = (dir == 0) ? NpadT : NpadP;
    const int Nx    = (dir == 0) ? N : M;
    if (sp * RPB >= NpadX) return;          // block-uniform

    const int TM  = NpadY / 32;
    const int nt0 = (TM + YS - 1) / YS;
    const int t0  = js * nt0;
    const int nt  = min(TM - t0, nt0);
    if (nt <= 0) return;                     // block-uniform

    __shared__ unsigned short ypack[YTILE_T * 32 * 16];  // 32 KB

    // A-frag (loop-invariant): row = lane&31, k = (lane>>5)*8 + e
    const int row0 = sp * RPB + w * 32;
    const short8 a = *reinterpret_cast<const short8*>(
        Xp + ((size_t)b * NpadX + row0 + lc) * 16 + (size_t)h * 8);

    f32x16 z, rm;
    #pragma unroll
    for (int r = 0; r < 16; ++r) { z[r] = 0.0f; rm[r] = __builtin_inff(); }

    for (int f0 = 0; f0 < nt; f0 += YTILE_T) {
        const int fc = min(YTILE_T, nt - f0);   // tiles this fill
        __syncthreads();
        {   // stage fc tiles (1 KB each), PERMUTED so reads are linear:
            // src 16B-unit v within tile: point p=v>>1, khalf h=v&1
            // dst unit = h*32 + p  ->  lane l reads point l&31, khalf l>>5
            const unsigned short* src =
                Yp + ((size_t)b * NpadY + (size_t)(t0 + f0) * 32) * 16;
            const int units = fc * 64;
            for (int u = tid; u < units; u += 256) {
                const int tile = u >> 6, v = u & 63;
                const int dst  = (tile << 6) | ((v & 1) << 5) | (v >> 1);
                *(uint4*)&ypack[(size_t)dst * 8] =
                    *(const uint4*)(src + (size_t)u * 8);
            }
        }
        __syncthreads();

        // B-frag: linear lane*16B within the tile (conflict-free)
        int j = 0;
        for (; j + 2 <= fc; j += 2) {
            const short8 b0 = *reinterpret_cast<const short8*>(
                &ypack[(size_t)j * 512 + (size_t)lane * 8]);
            const short8 b1 = *reinterpret_cast<const short8*>(
                &ypack[(size_t)(j + 1) * 512 + (size_t)lane * 8]);
            const f32x16 d0 =
                __builtin_amdgcn_mfma_f32_32x32x16_bf16(a, b0, z, 0, 0, 0);
            const f32x16 d1 =
                __builtin_amdgcn_mfma_f32_32x32x16_bf16(a, b1, z, 0, 0, 0);
            #pragma unroll
            for (int r = 0; r < 16; ++r)         // fuses to v_min3_f32
                rm[r] = fminf(fminf(d0[r], d1[r]), rm[r]);
        }
        if (j < fc) {
            const short8 b0 = *reinterpret_cast<const short8*>(
                &ypack[(size_t)j * 512 + (size_t)lane * 8]);
            const f32x16 d0 =
                __builtin_amdgcn_mfma_f32_32x32x16_bf16(a, b0, z, 0, 0, 0);
            #pragma unroll
            for (int r = 0; r < 16; ++r)
                rm[r] = fminf(rm[r], d0[r]);
        }
    }

    // cross-lane min over 32 cols; D layout: col=lane&31,
    // row=(r&3)+8*(r>>2)+4*(lane>>5)
    const size_t outb = (((size_t)dir * B + b) * YS + js) * (size_t)NpadMax;
    #pragma unroll
    for (int r = 0; r < 16; ++r) {
        float v = rm[r];
        #pragma unroll
        for (int mk = 1; mk <= 16; mk <<= 1)
            v = fminf(v, __shfl_xor(v, mk, 64));
        const int row = row0 + (r & 3) + 8 * (r >> 2) + 4 * h;
        if (lc == 0 && row < Nx) rowpart[outb + row] = v;
    }
}

__global__ __launch_bounds__(256) void combine_kernel(
    const float* __restrict__ rowpart, int B, int N, int M,
    int NpadP, int NpadT, int NpadMax,
    float invBN, float invBM, float* __restrict__ partial)
{
    const int tid = threadIdx.x;
    const int tot = 2 * B * NpadMax;
    float acc = 0.f;
    for (int idx = blockIdx.x * 256 + tid; idx < tot; idx += gridDim.x * 256) {
        const int row = idx % NpadMax;
        const int rem = idx / NpadMax;
        const int b   = rem % B;
        const int dir = rem / B;
        const int Nx  = (dir == 0) ? N : M;
        if (row >= Nx) continue;
        const int NpadY = (dir == 0) ? NpadT : NpadP;
        const int TM  = NpadY / 32;
        const int nt0 = (TM + YS - 1) / YS;
        float m = __builtin_inff();
        #pragma unroll
        for (int js = 0; js < YS; ++js)
            if (js * nt0 < TM)
                m = fminf(m, rowpart[(((size_t)dir * B + b) * YS + js)
                                     * (size_t)NpadMax + row]);
        acc += fmaxf(m, 0.f) * ((dir == 0) ? invBN : invBM);
    }
    __shared__ float sb[256];
    sb[tid] = acc; __syncthreads();
    for (int off2 = 128; off2 > 0; off2 >>= 1) {
        if (tid < off2) sb[tid] += sb[tid + off2];
        __syncthreads();
    }
    if (tid == 0) partial[blockIdx.x] = sb[0];
}

__global__ void finalize_kernel(const float* __restrict__ partial, int np,
                                const float* __restrict__ fbpp, int Bf,
                                const void* __restrict__ lamp,
                                float* __restrict__ out)
{
    __shared__ float sb[256];
    const int tid = threadIdx.x;
    float acc = 0.f;
    for (int i = tid; i < np; i += 256) acc += partial[i];
    sb[tid] = acc;
    __syncthreads();
    for (int off = 128; off > 0; off >>= 1) {
        if (tid < off) sb[tid] += sb[tid + off];
        __syncthreads();
    }
    if (tid == 0) {
        const int li = *(const int*)lamp;
        const float lam = (li >= -1000000 && li <= 1000000)
                            ? (float)li : *(const float*)lamp;
        float fm = 0.f;
        for (int i = 0; i < Bf; ++i) fm += fbpp[i];
        fm /= (float)Bf;
        out[0] = sb[0] + lam * fm;
    }
}

extern "C" void kernel_launch(void* const* d_in, const int* in_sizes, int n_in,
                              void* d_out, int out_size, void* d_ws, size_t ws_size,
                              hipStream_t stream) {
    const float* pred = (const float*)d_in[0];
    const float* targ = (const float*)d_in[1];
    const float* fbpp = (const float*)d_in[2];
    const void*  lamp = d_in[3];

    const int B = in_sizes[2];
    const int N = in_sizes[0] / (3 * B);
    const int M = in_sizes[1] / (3 * B);
    const int NpadP = roundup_h(N, RPB);
    const int NpadT = roundup_h(M, RPB);
    const int NpadMax = (NpadP > NpadT) ? NpadP : NpadT;

    // ---- workspace layout ----
    size_t o = 0;
    auto take = [&](size_t bytes) {
        size_t r = o; o += (bytes + 255) & ~(size_t)255; return r;
    };
    unsigned short* aP = (unsigned short*)((char*)d_ws +
                         take(((size_t)B * NpadP + 64) * 32));
    unsigned short* bP = (unsigned short*)((char*)d_ws +
                         take(((size_t)B * NpadP + 64) * 32));
    unsigned short* aT = (unsigned short*)((char*)d_ws +
                         take(((size_t)B * NpadT + 64) * 32));
    unsigned short* bT = (unsigned short*)((char*)d_ws +
                         take(((size_t)B * NpadT + 64) * 32));
    float* rowpart = (float*)((char*)d_ws +
                     take((size_t)2 * B * YS * NpadMax * sizeof(float)));
    float* partial = (float*)((char*)d_ws + take(256 * sizeof(float)));
    (void)ws_size;

    // ---- 1) pack both clouds into A/B MFMA K-patterns ----
    pack_kernel<<<(B * NpadMax + 255) / 256, 256, 0, stream>>>(
        pred, targ, B, N, M, NpadP, NpadT, aP, bP, aT, bT);

    // ---- 2) MFMA pair sweep (both directions) ----
    const int SP = NpadMax / RPB;
    const int blocks = 2 * B * YS * SP;
    mfma_sweep<<<blocks, 256, 0, stream>>>(
        aP, bP, aT, bT, B, N, M, NpadP, NpadT, NpadMax, rowpart);

    // ---- 3) combine js splits + clamp + weighted sum ----
    combine_kernel<<<256, 256, 0, stream>>>(
        rowpart, B, N, M, NpadP, NpadT, NpadMax,
        1.f / ((float)B * (float)N), 1.f / ((float)B * (float)M), partial);

    // ---- 4) finalize ----
    finalize_kernel<<<1, 256, 0, stream>>>(partial, 256, fbpp, B, lamp,
                                           (float*)d_out);
}

// Round 8
// 44.702 us; speedup vs baseline: 1.7044x; 1.1416x over previous
//
#include <hip/hip_runtime.h>
#include <math.h>

// Chamfer loss via MFMA: d2_ij = |x_i|^2 + |y_j|^2 - 2 x_i.y_j as ONE
// v_mfma_f32_32x32x16_bf16 per 32x32 tile using bf16-split K-packing:
//  k0-2 : A=-2xh_c  B=yh_c      k3-5 : A=-2xl_c  B=yh_c
//  k6-8 : A=-2xh_c  B=yl_c      k9-11: A=-2xl_c  B=yl_c
//  k12  : A=1 B=y2h   k13: A=1 B=y2l   k14: A=x2h B=1   k15: A=x2l B=1
// (packing + LDS permute verified round 7, absmax 0.0)
// Round-8 fix vs round 7: pin MFMA accumulators to arch VGPRs via zero-cost
// empty-asm "+v" constraints (round 7 put D/C in AGPRs: ~40 extra VALU
// accvgpr ops per tile, VALUBusy 62%). launch_bounds(256,4) caps at 128
// unified regs -> 4 waves/SIMD; data fits (~95 regs), no spill.

typedef __attribute__((ext_vector_type(8)))  short  short8;
typedef __attribute__((ext_vector_type(16))) float  f32x16;

#define YS      4     // j-range splits per (dir,b)
#define RPB     128   // rows per block = 4 waves * 32
#define YTILE_T 32    // 32-col tiles per LDS fill (1024 pts, 32 KB)

static inline int roundup_h(int v, int a) { return (v + a - 1) / a * a; }

static __device__ __forceinline__ unsigned short f2bf(float f) {
    union { float f; unsigned int u; } v; v.f = f;
    unsigned int r = v.u + 0x7FFFu + ((v.u >> 16) & 1u);  // RNE
    return (unsigned short)(r >> 16);
}
static __device__ __forceinline__ float bf2f(unsigned short s) {
    union { unsigned int u; float f; } v; v.u = ((unsigned int)s) << 16;
    return v.f;
}
static __device__ __forceinline__ unsigned int pk2(unsigned short lo,
                                                   unsigned short hi) {
    return (unsigned int)lo | ((unsigned int)hi << 16);
}

__global__ __launch_bounds__(256) void pack_kernel(
    const float* __restrict__ pred, const float* __restrict__ targ,
    int B, int N, int M, int NpadP, int NpadT,
    unsigned short* __restrict__ aP, unsigned short* __restrict__ bP,
    unsigned short* __restrict__ aT, unsigned short* __restrict__ bT)
{
    const int padmax = (NpadP > NpadT) ? NpadP : NpadT;
    const int gid = blockIdx.x * 256 + threadIdx.x;
    if (gid >= B * padmax) return;
    const int b = gid / padmax, i = gid - b * padmax;

    for (int cloud = 0; cloud < 2; ++cloud) {
        const int cnt  = cloud ? M : N;
        const int npad = cloud ? NpadT : NpadP;
        if (i >= npad) continue;
        // padding duplicates the last point: harmless for min reductions
        const float* src = (cloud ? targ : pred) +
                           ((size_t)b * cnt + min(i, cnt - 1)) * 3;
        unsigned short* A  = (cloud ? aT : aP) + ((size_t)b * npad + i) * 16;
        unsigned short* Bk = (cloud ? bT : bP) + ((size_t)b * npad + i) * 16;

        const float xs[3] = {src[0], src[1], src[2]};
        const float n2 = xs[0]*xs[0] + xs[1]*xs[1] + xs[2]*xs[2];
        unsigned short th[3], tl[3], yh[3], yl[3];
        #pragma unroll
        for (int c = 0; c < 3; ++c) {
            const float t = -2.0f * xs[c];
            th[c] = f2bf(t);     tl[c] = f2bf(t - bf2f(th[c]));
            yh[c] = f2bf(xs[c]); yl[c] = f2bf(xs[c] - bf2f(yh[c]));
        }
        const unsigned short n2h = f2bf(n2);
        const unsigned short n2l = f2bf(n2 - bf2f(n2h));
        const unsigned short ONE = 0x3F80;

        uint4 alo, ahi, blo, bhi;
        alo.x = pk2(th[0], th[1]); alo.y = pk2(th[2], tl[0]);
        alo.z = pk2(tl[1], tl[2]); alo.w = pk2(th[0], th[1]);
        ahi.x = pk2(th[2], tl[0]); ahi.y = pk2(tl[1], tl[2]);
        ahi.z = pk2(ONE,  ONE);    ahi.w = pk2(n2h,  n2l);
        blo.x = pk2(yh[0], yh[1]); blo.y = pk2(yh[2], yh[0]);
        blo.z = pk2(yh[1], yh[2]); blo.w = pk2(yl[0], yl[1]);
        bhi.x = pk2(yl[2], yl[0]); bhi.y = pk2(yl[1], yl[2]);
        bhi.z = pk2(n2h,  n2l);    bhi.w = pk2(ONE,  ONE);

        *(uint4*)(A)      = alo;  *(uint4*)(A + 8)  = ahi;
        *(uint4*)(Bk)     = blo;  *(uint4*)(Bk + 8) = bhi;
    }
}

// Block = (dir, b, js, row-block of 128). 4 waves, wave w owns rows
// [sp*128 + w*32, +32). Y-pack staged (permuted) in LDS, shared by all
// waves. Per 32-col tile: 1 linear ds_read_b128 + 1 MFMA + 8 fused min3.
__global__ __launch_bounds__(256, 4) void mfma_sweep(
    const unsigned short* __restrict__ aP, const unsigned short* __restrict__ bP,
    const unsigned short* __restrict__ aT, const unsigned short* __restrict__ bT,
    int B, int N, int M, int NpadP, int NpadT, int NpadMax,
    float* __restrict__ rowpart)
{
    const int tid  = threadIdx.x;
    const int w    = tid >> 6;
    const int lane = tid & 63;
    const int lc   = lane & 31, h = lane >> 5;

    const int SP = NpadMax / RPB;
    int t = blockIdx.x;
    const int sp  = t % SP;  t /= SP;
    const int js  = t % YS;  t /= YS;
    const int b   = t % B;   t /= B;
    const int dir = t;

    const unsigned short* Xp = (dir == 0) ? aP : aT;
    const unsigned short* Yp = (dir == 0) ? bT : bP;
    const int NpadX = (dir == 0) ? NpadP : NpadT;
    const int NpadY = (dir == 0) ? NpadT : NpadP;
    const int Nx    = (dir == 0) ? N : M;
    if (sp * RPB >= NpadX) return;          // block-uniform

    const int TM  = NpadY / 32;
    const int nt0 = (TM + YS - 1) / YS;
    const int t0  = js * nt0;
    const int nt  = min(TM - t0, nt0);
    if (nt <= 0) return;                     // block-uniform

    __shared__ unsigned short ypack[YTILE_T * 32 * 16];  // 32 KB

    // A-frag (loop-invariant): row = lane&31, k = (lane>>5)*8 + e
    const int row0 = sp * RPB + w * 32;
    const short8 a = *reinterpret_cast<const short8*>(
        Xp + ((size_t)b * NpadX + row0 + lc) * 16 + (size_t)h * 8);

    f32x16 z, rm;
    #pragma unroll
    for (int r = 0; r < 16; ++r) { z[r] = 0.0f; rm[r] = __builtin_inff(); }
    asm("" : "+v"(z));          // pin C operand to arch VGPRs (zero-cost)

    for (int f0 = 0; f0 < nt; f0 += YTILE_T) {
        const int fc = min(YTILE_T, nt - f0);   // tiles this fill
        __syncthreads();
        {   // stage fc tiles (1 KB each), PERMUTED so reads are linear:
            // src 16B-unit v within tile: point p=v>>1, khalf h=v&1
            // dst unit = h*32 + p  ->  lane l reads point l&31, khalf l>>5
            const unsigned short* src =
                Yp + ((size_t)b * NpadY + (size_t)(t0 + f0) * 32) * 16;
            const int units = fc * 64;
            for (int u = tid; u < units; u += 256) {
                const int tile = u >> 6, v = u & 63;
                const int dst  = (tile << 6) | ((v & 1) << 5) | (v >> 1);
                *(uint4*)&ypack[(size_t)dst * 8] =
                    *(const uint4*)(src + (size_t)u * 8);
            }
        }
        __syncthreads();

        // B-frag: linear lane*16B within the tile (conflict-free)
        int j = 0;
        for (; j + 2 <= fc; j += 2) {
            const short8 b0 = *reinterpret_cast<const short8*>(
                &ypack[(size_t)j * 512 + (size_t)lane * 8]);
            const short8 b1 = *reinterpret_cast<const short8*>(
                &ypack[(size_t)(j + 1) * 512 + (size_t)lane * 8]);
            f32x16 d0 =
                __builtin_amdgcn_mfma_f32_32x32x16_bf16(a, b0, z, 0, 0, 0);
            f32x16 d1 =
                __builtin_amdgcn_mfma_f32_32x32x16_bf16(a, b1, z, 0, 0, 0);
            asm("" : "+v"(d0), "+v"(d1));   // pin results to arch VGPRs
            #pragma unroll
            for (int r = 0; r < 16; ++r)         // fuses to v_min3_f32
                rm[r] = fminf(fminf(d0[r], d1[r]), rm[r]);
        }
        if (j < fc) {
            const short8 b0 = *reinterpret_cast<const short8*>(
                &ypack[(size_t)j * 512 + (size_t)lane * 8]);
            f32x16 d0 =
                __builtin_amdgcn_mfma_f32_32x32x16_bf16(a, b0, z, 0, 0, 0);
            asm("" : "+v"(d0));
            #pragma unroll
            for (int r = 0; r < 16; ++r)
                rm[r] = fminf(rm[r], d0[r]);
        }
    }

    // cross-lane min over 32 cols; D layout: col=lane&31,
    // row=(r&3)+8*(r>>2)+4*(lane>>5)
    const size_t outb = (((size_t)dir * B + b) * YS + js) * (size_t)NpadMax;
    #pragma unroll
    for (int r = 0; r < 16; ++r) {
        float v = rm[r];
        #pragma unroll
        for (int mk = 1; mk <= 16; mk <<= 1)
            v = fminf(v, __shfl_xor(v, mk, 64));
        const int row = row0 + (r & 3) + 8 * (r >> 2) + 4 * h;
        if (lc == 0 && row < Nx) rowpart[outb + row] = v;
    }
}

__global__ __launch_bounds__(256) void combine_kernel(
    const float* __restrict__ rowpart, int B, int N, int M,
    int NpadP, int NpadT, int NpadMax,
    float invBN, float invBM, float* __restrict__ partial)
{
    const int tid = threadIdx.x;
    const int tot = 2 * B * NpadMax;
    float acc = 0.f;
    for (int idx = blockIdx.x * 256 + tid; idx < tot; idx += gridDim.x * 256) {
        const int row = idx % NpadMax;
        const int rem = idx / NpadMax;
        const int b   = rem % B;
        const int dir = rem / B;
        const int Nx  = (dir == 0) ? N : M;
        if (row >= Nx) continue;
        const int NpadY = (dir == 0) ? NpadT : NpadP;
        const int TM  = NpadY / 32;
        const int nt0 = (TM + YS - 1) / YS;
        float m = __builtin_inff();
        #pragma unroll
        for (int js = 0; js < YS; ++js)
            if (js * nt0 < TM)
                m = fminf(m, rowpart[(((size_t)dir * B + b) * YS + js)
                                     * (size_t)NpadMax + row]);
        acc += fmaxf(m, 0.f) * ((dir == 0) ? invBN : invBM);
    }
    __shared__ float sb[256];
    sb[tid] = acc; __syncthreads();
    for (int off2 = 128; off2 > 0; off2 >>= 1) {
        if (tid < off2) sb[tid] += sb[tid + off2];
        __syncthreads();
    }
    if (tid == 0) partial[blockIdx.x] = sb[0];
}

__global__ void finalize_kernel(const float* __restrict__ partial, int np,
                                const float* __restrict__ fbpp, int Bf,
                                const void* __restrict__ lamp,
                                float* __restrict__ out)
{
    __shared__ float sb[256];
    const int tid = threadIdx.x;
    float acc = 0.f;
    for (int i = tid; i < np; i += 256) acc += partial[i];
    sb[tid] = acc;
    __syncthreads();
    for (int off = 128; off > 0; off >>= 1) {
        if (tid < off) sb[tid] += sb[tid + off];
        __syncthreads();
    }
    if (tid == 0) {
        const int li = *(const int*)lamp;
        const float lam = (li >= -1000000 && li <= 1000000)
                            ? (float)li : *(const float*)lamp;
        float fm = 0.f;
        for (int i = 0; i < Bf; ++i) fm += fbpp[i];
        fm /= (float)Bf;
        out[0] = sb[0] + lam * fm;
    }
}

extern "C" void kernel_launch(void* const* d_in, const int* in_sizes, int n_in,
                              void* d_out, int out_size, void* d_ws, size_t ws_size,
                              hipStream_t stream) {
    const float* pred = (const float*)d_in[0];
    const float* targ = (const float*)d_in[1];
    const float* fbpp = (const float*)d_in[2];
    const void*  lamp = d_in[3];

    const int B = in_sizes[2];
    const int N = in_sizes[0] / (3 * B);
    const int M = in_sizes[1] / (3 * B);
    const int NpadP = roundup_h(N, RPB);
    const int NpadT = roundup_h(M, RPB);
    const int NpadMax = (NpadP > NpadT) ? NpadP : NpadT;

    // ---- workspace layout ----
    size_t o = 0;
    auto take = [&](size_t bytes) {
        size_t r = o; o += (bytes + 255) & ~(size_t)255; return r;
    };
    unsigned short* aP = (unsigned short*)((char*)d_ws +
                         take(((size_t)B * NpadP + 64) * 32));
    unsigned short* bP = (unsigned short*)((char*)d_ws +
                         take(((size_t)B * NpadP + 64) * 32));
    unsigned short* aT = (unsigned short*)((char*)d_ws +
                         take(((size_t)B * NpadT + 64) * 32));
    unsigned short* bT = (unsigned short*)((char*)d_ws +
                         take(((size_t)B * NpadT + 64) * 32));
    float* rowpart = (float*)((char*)d_ws +
                     take((size_t)2 * B * YS * NpadMax * sizeof(float)));
    float* partial = (float*)((char*)d_ws + take(256 * sizeof(float)));
    (void)ws_size;

    // ---- 1) pack both clouds into A/B MFMA K-patterns ----
    pack_kernel<<<(B * NpadMax + 255) / 256, 256, 0, stream>>>(
        pred, targ, B, N, M, NpadP, NpadT, aP, bP, aT, bT);

    // ---- 2) MFMA pair sweep (both directions) ----
    const int SP = NpadMax / RPB;
    const int blocks = 2 * B * YS * SP;
    mfma_sweep<<<blocks, 256, 0, stream>>>(
        aP, bP, aT, bT, B, N, M, NpadP, NpadT, NpadMax, rowpart);

    // ---- 3) combine js splits + clamp + weighted sum ----
    combine_kernel<<<256, 256, 0, stream>>>(
        rowpart, B, N, M, NpadP, NpadT, NpadMax,
        1.f / ((float)B * (float)N), 1.f / ((float)B * (float)M), partial);

    // ---- 4) finalize ----
    finalize_kernel<<<1, 256, 0, stream>>>(partial, 256, fbpp, B, lamp,
                                           (float*)d_out);
}